// Round 3
// baseline (111.284 us; speedup 1.0000x reference)
//
#include <hip/hip_runtime.h>

// Problem constants (from reference)
#define CLASSES    128
#define M_IN       64
#define N_OUT      32
#define N_SAMPLES  65536
#define BUCKET_CAP N_SAMPLES   // per-class capacity: overflow structurally impossible

// ---------------- Phase 0: zero the per-class counters ----------------
__global__ __launch_bounds__(128) void zero_cnt_kernel(int* __restrict__ cnt) {
    cnt[threadIdx.x] = 0;
}

// ---------------- Phase 1: bucket samples by class ----------------
// 64 blocks x 256 threads, 4 samples/thread. Block-local LDS histogram ->
// one global atomicAdd per (block,class) -> scatter sample ids.
__global__ __launch_bounds__(256) void scatter_kernel(
    const int* __restrict__ inds,
    int*       __restrict__ cnt,      // [CLASSES]
    int*       __restrict__ bucket)   // [CLASSES][BUCKET_CAP]
{
    __shared__ int lcnt[CLASSES];
    __shared__ int lbase[CLASSES];
    const int tid = threadIdx.x;
    if (tid < CLASSES) lcnt[tid] = 0;
    __syncthreads();

    int c_k[4], lpos[4], ii[4];
#pragma unroll
    for (int k = 0; k < 4; ++k) {
        ii[k]  = blockIdx.x * 1024 + k * 256 + tid;   // coalesced
        c_k[k] = inds[ii[k]];
        lpos[k] = atomicAdd(&lcnt[c_k[k]], 1);        // LDS atomic
    }
    __syncthreads();

    if (tid < CLASSES) lbase[tid] = atomicAdd(&cnt[tid], lcnt[tid]); // device-scope
    __syncthreads();

#pragma unroll
    for (int k = 0; k < 4; ++k) {
        bucket[c_k[k] * BUCKET_CAP + lbase[c_k[k]] + lpos[k]] = ii[k];
    }
}

// ---------------- Phase 2: compute from LDS-resident W slice ----------------
// Grid = CLASSES * 8 blocks; block (c, j) stages W[c] (8 KB) into LDS, then
// 4 waves each serve samples p = t*32 + (j*4 + w) from bucket[c].
// Per sample (wave): coalesced 256 B x-row read, 8 ds_read_b128 W-frags,
// dot4 + 16-lane butterfly, LDS transpose, coalesced 128 B store.
__global__ __launch_bounds__(256) void compute_kernel(
    const float* __restrict__ x,      // (N_SAMPLES, M_IN)
    const float* __restrict__ W,      // (CLASSES*N_OUT, M_IN)
    const float* __restrict__ b,      // (CLASSES*N_OUT,)
    const int*   __restrict__ cnt,    // [CLASSES]
    const int*   __restrict__ bucket, // [CLASSES][BUCKET_CAP]
    float*       __restrict__ out)    // (N_SAMPLES, N_OUT)
{
    __shared__ float4 Ws4[N_OUT * M_IN / 4];   // 512 float4 = 8 KB
    __shared__ float  slots[4 * N_OUT];        // per-wave transpose slot

    const int c    = blockIdx.x >> 3;
    const int j    = blockIdx.x & 7;
    const int tid  = threadIdx.x;
    const int w    = tid >> 6;
    const int lane = tid & 63;
    const int m    = lane & 15;   // k-chunk
    const int q    = lane >> 4;   // row % 4

    // Stage W slice: 2 coalesced float4 loads per thread
    const float4* Wb4 = reinterpret_cast<const float4*>(W) + (size_t)c * (N_OUT * M_IN / 4);
    Ws4[tid]       = Wb4[tid];
    Ws4[tid + 256] = Wb4[tid + 256];

    const int cntc = cnt[c];
    __syncthreads();

    const float bv = (lane < N_OUT) ? b[c * N_OUT + lane] : 0.0f;
    const int   id = j * 4 + w;                 // this wave's stream id, 0..31
    const int   T  = (cntc + 31) >> 5;          // block-uniform trip count
    float* slot = slots + (w << 5);
    const float4* x4 = reinterpret_cast<const float4*>(x);
    const int* bk = bucket + c * BUCKET_CAP;

    for (int t = 0; t < T; ++t) {
        const int  p     = (t << 5) + id;
        const bool valid = p < cntc;
        const int  n     = valid ? bk[p] : 0;   // wave-uniform broadcast load

        const float4 xv = x4[(size_t)n * 16 + m];   // one 256 B row / wave

        float pr[8];
#pragma unroll
        for (int i = 0; i < 8; ++i) {
            const float4 wv = Ws4[i * 64 + lane];   // contiguous ds_read_b128
            pr[i] = wv.x * xv.x + wv.y * xv.y + wv.z * xv.z + wv.w * xv.w;
        }

        // Reduce over the 16-lane k-group (masks 8,4,2,1 stay in-group)
#pragma unroll
        for (int i = 0; i < 8; ++i) {
#pragma unroll
            for (int off = 8; off >= 1; off >>= 1)
                pr[i] += __shfl_xor(pr[i], off, 64);
        }

        // Transpose: lane m==0 of row-group q holds rows {4i+q}
        if (m == 0) {
#pragma unroll
            for (int i = 0; i < 8; ++i) slot[i * 4 + q] = pr[i];
        }
        __syncthreads();   // equal T across all waves -> legal
        if (valid && lane < N_OUT)
            out[(size_t)n * N_OUT + lane] = slot[lane] + bv;   // coalesced 128 B
        __syncthreads();
    }
}

extern "C" void kernel_launch(void* const* d_in, const int* in_sizes, int n_in,
                              void* d_out, int out_size, void* d_ws, size_t ws_size,
                              hipStream_t stream) {
    const float* x    = (const float*)d_in[0];
    const int*   inds = (const int*)  d_in[1];
    const float* W    = (const float*)d_in[2];
    const float* b    = (const float*)d_in[3];
    float*       out  = (float*)d_out;

    int* cnt    = (int*)d_ws;            // 128 ints
    int* bucket = (int*)d_ws + 1024;     // 4 KB offset; 128*65536 ints = 32 MB

    zero_cnt_kernel<<<1, 128, 0, stream>>>(cnt);
    scatter_kernel<<<N_SAMPLES / 1024, 256, 0, stream>>>(inds, cnt, bucket);
    compute_kernel<<<CLASSES * 8, 256, 0, stream>>>(x, W, b, cnt, bucket, out);
}

// Round 4
// 83.966 us; speedup vs baseline: 1.3253x; 1.3253x over previous
//
#include <hip/hip_runtime.h>

// Problem constants (from reference)
#define CLASSES    128
#define M_IN       64
#define N_OUT      32
#define N_SAMPLES  65536
#define BUCKET_CAP N_SAMPLES

typedef __attribute__((ext_vector_type(8))) short bf16x8;  // MFMA A/B frag (4 VGPRs)
typedef __attribute__((ext_vector_type(4))) float f32x4;   // MFMA C/D frag

// fp32 -> bf16, round-to-nearest-even (bit trick; no NaN inputs here)
__device__ inline short f2bf(float f) {
    unsigned u = __builtin_bit_cast(unsigned, f);
    u += 0x7fffu + ((u >> 16) & 1u);
    return (short)(u >> 16);
}

__device__ inline bf16x8 cvt8(const float4 a, const float4 b) {
    bf16x8 r;
    r[0] = f2bf(a.x); r[1] = f2bf(a.y); r[2] = f2bf(a.z); r[3] = f2bf(a.w);
    r[4] = f2bf(b.x); r[5] = f2bf(b.y); r[6] = f2bf(b.z); r[7] = f2bf(b.w);
    return r;
}

// ---------------- Phase 0: zero per-class counters ----------------
__global__ __launch_bounds__(128) void zero_cnt_kernel(int* __restrict__ cnt) {
    cnt[threadIdx.x] = 0;
}

// ---------------- Phase 1: bucket samples by class ----------------
// 256 blocks x 256 threads, 1 sample/thread. LDS histogram -> one global
// atomicAdd per (block,class) -> scatter.
__global__ __launch_bounds__(256) void scatter_kernel(
    const int* __restrict__ inds,
    int*       __restrict__ cnt,
    int*       __restrict__ bucket)
{
    __shared__ int lcnt[CLASSES];
    __shared__ int lbase[CLASSES];
    const int tid = threadIdx.x;
    if (tid < CLASSES) lcnt[tid] = 0;
    __syncthreads();

    const int i    = blockIdx.x * 256 + tid;   // coalesced
    const int c    = inds[i];
    const int lpos = atomicAdd(&lcnt[c], 1);   // LDS atomic, ~2 hits/class/block
    __syncthreads();

    if (tid < CLASSES) lbase[tid] = atomicAdd(&cnt[tid], lcnt[tid]);
    __syncthreads();

    bucket[c * BUCKET_CAP + lbase[c] + lpos] = i;
}

// ---------------- Phase 2: MFMA compute, no LDS, no shuffles ----------------
// Grid = CLASSES*8 blocks x 4 waves. Wave stream s = (blk&7)*4+wave handles
// 16-sample tiles t = s, s+32, ... of its class. Per tile: 4 x-row gather
// loads (32 B/lane), 4 MFMAs (K=64, N=32), guarded scatter-store.
__global__ __launch_bounds__(256) void compute_kernel(
    const float* __restrict__ x,      // (N_SAMPLES, 64)
    const float* __restrict__ W,      // (CLASSES*32, 64)
    const float* __restrict__ b,      // (CLASSES*32,)
    const int*   __restrict__ cnt,    // [CLASSES]
    const int*   __restrict__ bucket, // [CLASSES][BUCKET_CAP]
    float*       __restrict__ out)    // (N_SAMPLES, 32)
{
    const int c    = blockIdx.x >> 3;
    const int j8   = blockIdx.x & 7;
    const int wv   = threadIdx.x >> 6;
    const int lane = threadIdx.x & 63;
    const int m16  = lane & 15;   // M-row / N-col / C-col selector
    const int quad = lane >> 4;   // K-chunk selector (k = quad*8 + j)

    // B frags: B[k][n] = W[c*32 + n][k]; lane holds n = nh*16 + m16,
    // k = kh*32 + quad*8 + j  -> 8 consecutive fp32 from W row (32 B aligned)
    bf16x8 Bf[2][2];
#pragma unroll
    for (int nh = 0; nh < 2; ++nh)
#pragma unroll
        for (int kh = 0; kh < 2; ++kh) {
            const float* p = W + (size_t)(c * N_OUT + nh * 16 + m16) * M_IN
                               + kh * 32 + quad * 8;
            Bf[nh][kh] = cvt8(*(const float4*)p, *(const float4*)(p + 4));
        }

    const float b0 = b[c * N_OUT + m16];        // bias for C-col m16
    const float b1 = b[c * N_OUT + 16 + m16];   // bias for C-col 16+m16

    const int cn = cnt[c];
    if (cn == 0) return;
    const int T = (cn + 15) >> 4;
    const int* bk = bucket + c * BUCKET_CAP;

    for (int t = j8 * 4 + wv; t < T; t += 32) {
        const int base = t << 4;

        // A frags: lane holds x[row m16 of tile][k = kh*32 + quad*8 + j]
        const int pa = base + m16;
        const int na = bk[(pa < cn) ? pa : (cn - 1)];   // 64 B line, broadcast/quad
        const float* xr = x + (size_t)na * M_IN + quad * 8;
        const bf16x8 A0 = cvt8(*(const float4*)xr,        *(const float4*)(xr + 4));
        const bf16x8 A1 = cvt8(*(const float4*)(xr + 32), *(const float4*)(xr + 36));

        f32x4 acc0 = {0.f, 0.f, 0.f, 0.f};
        f32x4 acc1 = {0.f, 0.f, 0.f, 0.f};
        acc0 = __builtin_amdgcn_mfma_f32_16x16x32_bf16(A0, Bf[0][0], acc0, 0, 0, 0);
        acc0 = __builtin_amdgcn_mfma_f32_16x16x32_bf16(A1, Bf[0][1], acc0, 0, 0, 0);
        acc1 = __builtin_amdgcn_mfma_f32_16x16x32_bf16(A0, Bf[1][0], acc1, 0, 0, 0);
        acc1 = __builtin_amdgcn_mfma_f32_16x16x32_bf16(A1, Bf[1][1], acc1, 0, 0, 0);

        // C layout: col = m16, row = quad*4 + r
#pragma unroll
        for (int r = 0; r < 4; ++r) {
            const int p = base + quad * 4 + r;
            if (p < cn) {
                const int n = bk[p];                     // broadcast within quad
                out[(size_t)n * N_OUT + m16]      = acc0[r] + b0;
                out[(size_t)n * N_OUT + 16 + m16] = acc1[r] + b1;
            }
        }
    }
}

extern "C" void kernel_launch(void* const* d_in, const int* in_sizes, int n_in,
                              void* d_out, int out_size, void* d_ws, size_t ws_size,
                              hipStream_t stream) {
    const float* x    = (const float*)d_in[0];
    const int*   inds = (const int*)  d_in[1];
    const float* W    = (const float*)d_in[2];
    const float* b    = (const float*)d_in[3];
    float*       out  = (float*)d_out;

    int* cnt    = (int*)d_ws;            // 128 ints
    int* bucket = (int*)d_ws + 1024;     // 4 KB offset; 128*65536 ints = 32 MB

    zero_cnt_kernel<<<1, 128, 0, stream>>>(cnt);
    scatter_kernel<<<N_SAMPLES / 256, 256, 0, stream>>>(inds, cnt, bucket);
    compute_kernel<<<CLASSES * 8, 256, 0, stream>>>(x, W, b, cnt, bucket, out);
}

// Round 5
// 80.908 us; speedup vs baseline: 1.3754x; 1.0378x over previous
//
#include <hip/hip_runtime.h>

// Problem constants (from reference)
#define CLASSES    128
#define M_IN       64
#define N_OUT      32
#define N_SAMPLES  65536
#define BUCKET_CAP N_SAMPLES

typedef __attribute__((ext_vector_type(8))) short bf16x8;  // MFMA A/B frag (4 VGPRs)
typedef __attribute__((ext_vector_type(4))) float f32x4;   // MFMA C/D frag

// fp32 -> bf16, round-to-nearest-even (bit trick; no NaN inputs here)
__device__ inline short f2bf(float f) {
    unsigned u = __builtin_bit_cast(unsigned, f);
    u += 0x7fffu + ((u >> 16) & 1u);
    return (short)(u >> 16);
}

__device__ inline bf16x8 cvt8(const float4 a, const float4 b) {
    bf16x8 r;
    r[0] = f2bf(a.x); r[1] = f2bf(a.y); r[2] = f2bf(a.z); r[3] = f2bf(a.w);
    r[4] = f2bf(b.x); r[5] = f2bf(b.y); r[6] = f2bf(b.z); r[7] = f2bf(b.w);
    return r;
}

// ---------------- Phase 1: bucket samples by class ----------------
// 128 blocks x 256 threads x 2 samples (int2). LDS histogram -> one global
// atomicAdd per (block,class) -> scatter sample ids.
__global__ __launch_bounds__(256) void scatter_kernel(
    const int* __restrict__ inds,
    int*       __restrict__ cnt,      // [CLASSES] (pre-zeroed via memset)
    int*       __restrict__ bucket)   // [CLASSES][BUCKET_CAP]
{
    __shared__ int lcnt[CLASSES];
    __shared__ int lbase[CLASSES];
    const int tid = threadIdx.x;
    if (tid < CLASSES) lcnt[tid] = 0;
    __syncthreads();

    const int  vi = blockIdx.x * 256 + tid;        // int2 index, coalesced
    const int2 cc = reinterpret_cast<const int2*>(inds)[vi];
    const int  i0 = vi * 2, i1 = i0 + 1;
    const int  p0 = atomicAdd(&lcnt[cc.x], 1);     // LDS atomics
    const int  p1 = atomicAdd(&lcnt[cc.y], 1);
    __syncthreads();

    if (tid < CLASSES) lbase[tid] = atomicAdd(&cnt[tid], lcnt[tid]);
    __syncthreads();

    bucket[cc.x * BUCKET_CAP + lbase[cc.x] + p0] = i0;
    bucket[cc.y * BUCKET_CAP + lbase[cc.y] + p1] = i1;
}

// ---------------- Phase 2: MFMA compute, 2-stage software pipeline ----------
// Grid = CLASSES*4 blocks x 4 waves -> 16 streams/class, ~2 tiles/stream.
// Next tile's bucket+x loads are issued before current tile's cvt/MFMA/store.
__global__ __launch_bounds__(256) void compute_kernel(
    const float* __restrict__ x,      // (N_SAMPLES, 64)
    const float* __restrict__ W,      // (CLASSES*32, 64)
    const float* __restrict__ b,      // (CLASSES*32,)
    const int*   __restrict__ cnt,    // [CLASSES]
    const int*   __restrict__ bucket, // [CLASSES][BUCKET_CAP]
    float*       __restrict__ out)    // (N_SAMPLES, 32)
{
    const int c    = blockIdx.x >> 2;
    const int j4   = blockIdx.x & 3;
    const int wv   = threadIdx.x >> 6;
    const int lane = threadIdx.x & 63;
    const int m16  = lane & 15;   // M-row / N-col selector
    const int quad = lane >> 4;   // K-chunk selector

    const int  cn = cnt[c];
    const int* bk = bucket + c * BUCKET_CAP;

    // B frags: lane holds n = nh*16 + m16, k = kh*32 + quad*8 + j
    bf16x8 Bf[2][2];
#pragma unroll
    for (int nh = 0; nh < 2; ++nh)
#pragma unroll
        for (int kh = 0; kh < 2; ++kh) {
            const float* p = W + (size_t)(c * N_OUT + nh * 16 + m16) * M_IN
                               + kh * 32 + quad * 8;
            Bf[nh][kh] = cvt8(*(const float4*)p, *(const float4*)(p + 4));
        }
    const float b0 = b[c * N_OUT + m16];
    const float b1 = b[c * N_OUT + 16 + m16];

    if (cn == 0) return;
    const int T = (cn + 15) >> 4;
    int t = j4 * 4 + wv;          // stream id 0..15
    if (t >= T) return;

    // Prologue: load tile t
    int base = t << 4;
    {
        // fallthrough into loop with xa* live
    }
    int pa = base + m16;
    int na = bk[(pa < cn) ? pa : (cn - 1)];
    const float* xr = x + (size_t)na * M_IN + quad * 8;
    float4 xa0 = *(const float4*)xr,        xa1 = *(const float4*)(xr + 4);
    float4 xa2 = *(const float4*)(xr + 32), xa3 = *(const float4*)(xr + 36);

    while (true) {
        const int  tn   = t + 16;
        const bool more = tn < T;

        // Issue next tile's loads before touching current tile's data
        int base_n = base, na_n = na;
        float4 xb0 = xa0, xb1 = xa1, xb2 = xa2, xb3 = xa3;
        if (more) {
            base_n = tn << 4;
            const int pan = base_n + m16;
            na_n = bk[(pan < cn) ? pan : (cn - 1)];
            const float* xrn = x + (size_t)na_n * M_IN + quad * 8;
            xb0 = *(const float4*)xrn;        xb1 = *(const float4*)(xrn + 4);
            xb2 = *(const float4*)(xrn + 32); xb3 = *(const float4*)(xrn + 36);
        }

        // Compute current tile
        const bf16x8 A0 = cvt8(xa0, xa1);
        const bf16x8 A1 = cvt8(xa2, xa3);
        f32x4 acc0 = {0.f, 0.f, 0.f, 0.f};
        f32x4 acc1 = {0.f, 0.f, 0.f, 0.f};
        acc0 = __builtin_amdgcn_mfma_f32_16x16x32_bf16(A0, Bf[0][0], acc0, 0, 0, 0);
        acc0 = __builtin_amdgcn_mfma_f32_16x16x32_bf16(A1, Bf[0][1], acc0, 0, 0, 0);
        acc1 = __builtin_amdgcn_mfma_f32_16x16x32_bf16(A0, Bf[1][0], acc1, 0, 0, 0);
        acc1 = __builtin_amdgcn_mfma_f32_16x16x32_bf16(A1, Bf[1][1], acc1, 0, 0, 0);

        // C layout: col = m16, row = quad*4 + r
#pragma unroll
        for (int r = 0; r < 4; ++r) {
            const int p = base + quad * 4 + r;
            if (p < cn) {
                const int n = bk[p];              // L1-hot (same line as na gather)
                out[(size_t)n * N_OUT + m16]      = acc0[r] + b0;
                out[(size_t)n * N_OUT + 16 + m16] = acc1[r] + b1;
            }
        }

        if (!more) break;
        t = tn; base = base_n; na = na_n;
        xa0 = xb0; xa1 = xb1; xa2 = xb2; xa3 = xb3;
    }
}

extern "C" void kernel_launch(void* const* d_in, const int* in_sizes, int n_in,
                              void* d_out, int out_size, void* d_ws, size_t ws_size,
                              hipStream_t stream) {
    const float* x    = (const float*)d_in[0];
    const int*   inds = (const int*)  d_in[1];
    const float* W    = (const float*)d_in[2];
    const float* b    = (const float*)d_in[3];
    float*       out  = (float*)d_out;

    int* cnt    = (int*)d_ws;            // 128 ints
    int* bucket = (int*)d_ws + 1024;     // 4 KB offset; 128*65536 ints = 32 MB

    hipMemsetAsync(cnt, 0, CLASSES * sizeof(int), stream);   // graph-capturable
    scatter_kernel<<<N_SAMPLES / 512, 256, 0, stream>>>(inds, cnt, bucket);
    compute_kernel<<<CLASSES * 4, 256, 0, stream>>>(x, W, b, cnt, bucket, out);
}